// Round 11
// baseline (281.554 us; speedup 1.0000x reference)
//
#include <hip/hip_runtime.h>
#include <math.h>

#define B_   24
#define NA_  50
#define T_   10
#define NV_  196
#define D_   512
#define M_   1200          // B*NA audio rows
#define MPAD 1280          // padded to 10 tiles of 128
#define NVP  224           // 196 padded to 14*16
#define YT_  240           // B*T
#define VROWS (YT_ * NVP)  // 53760 padded visual rows
#define ABLK 320           // MPAD/4 blocks handle audio in fused normconv

#define NT    16           // K-steps (BK=32)
#define BUFB  22528u       // per-step buffer: A 8KB + V 14KB
#define VBASE 8192u

typedef __bf16 bf16x8 __attribute__((ext_vector_type(8)));
typedef float  f32x4  __attribute__((ext_vector_type(4)));
typedef unsigned short ushort8 __attribute__((ext_vector_type(8)));

__device__ __forceinline__ unsigned short f2bf(float f) {
    unsigned u = __float_as_uint(f);
    u += 0x7FFF + ((u >> 16) & 1);       // RNE
    return (unsigned short)(u >> 16);
}

__device__ __forceinline__ void gload16(const void* g, void* l) {
    __builtin_amdgcn_global_load_lds(
        (const __attribute__((address_space(1))) unsigned int*)g,
        (__attribute__((address_space(3))) unsigned int*)l, 16, 0, 0);
}

// ---- fused L2-normalize + bf16 convert for BOTH inputs, + accs/counter zeroing ----
__global__ void normconv_kernel(const float* __restrict__ a,
                                const float* __restrict__ vf,
                                const float* __restrict__ tempPtr,
                                unsigned short* __restrict__ Abf,
                                unsigned short* __restrict__ Vbf,
                                float* __restrict__ accs) {
    if (blockIdx.x == 0 && threadIdx.x < 4) accs[threadIdx.x] = 0.0f; // [nonneg,frac,sel,counter]
    int w = threadIdx.x >> 6, lane = threadIdx.x & 63;
    int bid = blockIdx.x;
    const float* src = nullptr;
    ushort8* dst;
    float tscale = 1.0f;
    if (bid < ABLK) {
        int row = bid * 4 + w;                 // < MPAD
        dst = (ushort8*)(Abf + (size_t)row * D_ + lane * 8);
        if (row < M_) { src = a + (size_t)row * D_ + lane * 8; tscale = tempPtr[0]; }
    } else {
        int row = (bid - ABLK) * 4 + w;        // < VROWS
        dst = (ushort8*)(Vbf + (size_t)row * D_ + lane * 8);
        int yt = row / NVP, vv = row - yt * NVP;
        if (vv < NV_) src = vf + ((size_t)yt * NV_ + vv) * D_ + lane * 8;
    }
    if (src) {
        float4 u = *(const float4*)src;
        float4 v = *(const float4*)(src + 4);
        float s = u.x*u.x + u.y*u.y + u.z*u.z + u.w*u.w
                + v.x*v.x + v.y*v.y + v.z*v.z + v.w*v.w;
        #pragma unroll
        for (int off = 32; off; off >>= 1) s += __shfl_xor(s, off, 64);
        float sc = 1.0f / (fmaxf(sqrtf(s), 1e-12f) * tscale);
        ushort8 o;
        o[0]=f2bf(u.x*sc); o[1]=f2bf(u.y*sc); o[2]=f2bf(u.z*sc); o[3]=f2bf(u.w*sc);
        o[4]=f2bf(v.x*sc); o[5]=f2bf(v.y*sc); o[6]=f2bf(v.z*sc); o[7]=f2bf(v.w*sc);
        *dst = o;
    } else {
        ushort8 z = (ushort8)0;
        *dst = z;
    }
}

// ---- MFMA GEMM + fused max/clip reductions: counted pipeline x 2 blocks/CU ----
// R10's verified schedule (reg-double-buffered frags, ONE raw s_barrier + ONE
// combined vmcnt/lgkm wait per step, STAGE(t+2) flying a full step ahead) at
// R3's 128x224 / 4-wave geometry. Unified-RF arithmetic (VGPR 120 + acc AGPR
// 112 = 232/wave -> 2 waves/SIMD cap) means 8 waves/CU either way; as ONE
// 8-wave block (R10) every barrier idles the whole CU. As TWO independent
// 4-wave blocks (45KB LDS each, both fit), the two barrier domains phase-
// offset and fill each other's waits. XCD bijective swizzle (FETCH 229->32MB,
// R3) + both-sides 16B-granule XOR LDS swizzle (conflicts->0, R1) retained.
#define RD_FRAGS(AF, BV, BASE)                                                  \
    _Pragma("unroll") for (int i = 0; i < 4; ++i)                               \
        AF[i] = *(const bf16x8*)((BASE) + aoff[i]);                             \
    _Pragma("unroll") for (int j = 0; j < 7; ++j)                               \
        BV[j] = *(const bf16x8*)((BASE) + boff[j]);

#define MFMA_ALL(AF, BV)                                                        \
    _Pragma("unroll") for (int i = 0; i < 4; ++i)                               \
        _Pragma("unroll") for (int j = 0; j < 7; ++j)                           \
            acc[i][j] = __builtin_amdgcn_mfma_f32_16x16x32_bf16(AF[i], BV[j], acc[i][j], 0, 0, 0);

#define STAGE_T(T, BASEOFF)                                                     \
    _Pragma("unroll") for (int k = 0; k < 6; ++k)                               \
        if (k < nun) gload16(gp[k] + (T) * 32, (void*)(lds + (BASEOFF) + loff[k]));

__global__ __launch_bounds__(256, 2) void simred_kernel(
    const unsigned short* __restrict__ Abf, const unsigned short* __restrict__ Vbf,
    float* __restrict__ maxvis, float* __restrict__ accNonneg)
{
    __shared__ __align__(16) unsigned char lds[2 * BUFB];   // 45KB: two blocks/CU fit
    __shared__ float maxred[2][128];
    __shared__ float redbuf[4];

    const int tid  = threadIdx.x;
    const int lane = tid & 63;
    const int w    = tid >> 6;     // 4 waves
    const int lrow = lane >> 2;    // staging: row within 16-row unit
    const int lcol = lane & 3;     // staging: 16B granule within 64B row-slice
    const int q    = lane >> 4;    // frag quad
    const int m16  = lane & 15;
    const int wr   = w & 1;        // wave row half (64 rows)
    const int wc   = w >> 1;       // wave col half (112 cols)

    // XCD-aware bijective remap: 2400 blocks, 8 XCDs, 300/XCD (yt-partitioned)
    const int lin = blockIdx.y * gridDim.x + blockIdx.x;
    const int swz = (lin & 7) * 300 + (lin >> 3);
    const int bx  = swz % 10;
    const int yt  = swz / 10;
    const int rowA0 = bx * 128;
    const size_t vRow0 = (size_t)yt * NVP;

    // staging units (1KB each): 0..7 = A rows u*16.., 8..21 = V rows (u-8)*16..
    // Source granule pre-swizzled; LDS dest linear (both-sides rule).
    const int scol = lcol ^ ((lrow >> 1) & 3);
    const unsigned short* gp[6];
    unsigned loff[6];
    int nun = 0;
    for (int u = w; u < 22; u += 4) {
        if (u < 8) gp[nun] = Abf + ((size_t)(rowA0 + u * 16 + lrow)) * D_ + scol * 8;
        else       gp[nun] = Vbf + (vRow0 + (size_t)((u - 8) * 16 + lrow)) * D_ + scol * 8;
        loff[nun] = (unsigned)u * 1024u;
        ++nun;
    }

    // fragment read offsets (row*64B + swizzled 16B granule)
    const unsigned rsw = (unsigned)((m16 >> 1) & 3) * 16u;
    unsigned aoff[4], boff[7];
    #pragma unroll
    for (int i = 0; i < 4; ++i)
        aoff[i] = (unsigned)(wr * 64 + i * 16 + m16) * 64u + (((unsigned)q * 16u) ^ rsw);
    #pragma unroll
    for (int j = 0; j < 7; ++j)
        boff[j] = VBASE + (unsigned)(wc * 112 + j * 16 + m16) * 64u + (((unsigned)q * 16u) ^ rsw);

    f32x4 acc[4][7];
    #pragma unroll
    for (int i = 0; i < 4; ++i)
        #pragma unroll
        for (int j = 0; j < 7; ++j) acc[i][j] = (f32x4)0.0f;

    bf16x8 afA[4], bvA[7], afB[4], bvB[7];

    // prologue: STAGE(0)->b0, STAGE(1)->b1; drain both (one-time ~500cyc);
    // frags(0)->A. (vmcnt(0) avoids per-wave non-uniform counted immediates.)
    STAGE_T(0, 0u)
    STAGE_T(1, BUFB)
    asm volatile("s_waitcnt vmcnt(0)\ns_barrier" ::: "memory");
    RD_FRAGS(afA, bvA, lds)

    #pragma unroll
    for (int tp = 0; tp < 8; ++tp) {
        const int t = 2 * tp;
        // ---- even step t: compute A (from b0), read frags(t+1) b1 -> B ----
        asm volatile("s_waitcnt vmcnt(0) lgkmcnt(0)\ns_barrier" ::: "memory");
        if (t + 2 < NT) { STAGE_T(t + 2, 0u) }          // -> b0 (just fully read)
        RD_FRAGS(afB, bvB, lds + BUFB)                  // frags(t+1)
        __builtin_amdgcn_s_setprio(1);
        MFMA_ALL(afA, bvA)
        __builtin_amdgcn_s_setprio(0);
        // ---- odd step t+1: compute B (from b1), read frags(t+2) b0 -> A ----
        asm volatile("s_waitcnt vmcnt(0) lgkmcnt(0)\ns_barrier" ::: "memory");
        if (t + 3 < NT) { STAGE_T(t + 3, BUFB) }        // -> b1
        if (t + 2 < NT) { RD_FRAGS(afA, bvA, lds) }     // frags(t+2)
        __builtin_amdgcn_s_setprio(1);
        MFMA_ALL(afB, bvB)
        __builtin_amdgcn_s_setprio(0);
    }

    // ---- clip(s,-20,0)^2 partial sum (zero-padded rows/cols contribute exactly 0) ----
    float cs = 0.0f;
    #pragma unroll
    for (int i = 0; i < 4; ++i)
        #pragma unroll
        for (int j = 0; j < 7; ++j)
            #pragma unroll
            for (int r = 0; r < 4; ++r) {
                float v = acc[i][j][r];
                float cv = fminf(fmaxf(v, -20.0f), 0.0f);
                cs += cv * cv;
            }
    #pragma unroll
    for (int off = 32; off; off >>= 1) cs += __shfl_xor(cs, off, 64);
    if (lane == 0) redbuf[w] = cs;

    // ---- per-row max over valid cols (C/D layout: col=lane&15, row=q*4+reg) ----
    bool colv[7];
    #pragma unroll
    for (int j = 0; j < 7; ++j) colv[j] = (wc * 112 + j * 16 + m16) < NV_;
    #pragma unroll
    for (int i = 0; i < 4; ++i) {
        float mx[4] = {-3e38f, -3e38f, -3e38f, -3e38f};
        #pragma unroll
        for (int j = 0; j < 7; ++j)
            #pragma unroll
            for (int r = 0; r < 4; ++r)
                mx[r] = fmaxf(mx[r], colv[j] ? acc[i][j][r] : -3e38f);
        #pragma unroll
        for (int r = 0; r < 4; ++r) {
            float mm = mx[r];
            #pragma unroll
            for (int off = 1; off <= 8; off <<= 1) mm = fmaxf(mm, __shfl_xor(mm, off, 64));
            if (m16 == 0) maxred[wc][wr * 64 + i * 16 + q * 4 + r] = mm;
        }
    }
    __syncthreads();
    if (tid == 0) atomicAdd(accNonneg, redbuf[0] + redbuf[1] + redbuf[2] + redbuf[3]);
    if (tid < 128) {
        float mm = fmaxf(maxred[0][tid], maxred[1][tid]);
        int R = rowA0 + tid;
        if (R < M_) {
            int x = R / NA_, a = R - x * NA_;
            int y = yt / T_, t = yt - y * T_;
            maxvis[(((size_t)x * B_ + y) * NA_ + a) * T_ + t] = mm;
        }
    }
}

// ---------------- aggregation + last-block finalize ----------------
__global__ void aggfin_kernel(const float* __restrict__ maxvis,
                              const float* __restrict__ thrPtr,
                              const float* __restrict__ scalePtr,
                              const float* __restrict__ tempPtr,
                              float* __restrict__ clipSims,
                              float* __restrict__ accs,
                              float* __restrict__ out)
{
    int xy = blockIdx.x;
    int x = xy / B_, y = xy % B_;
    int a = threadIdx.x;
    float th    = 1.0f / (1.0f + expf(-thrPtr[0]));
    float scale = scalePtr[0];
    float token = 0.0f, cnt = 0.0f, selsum = 0.0f;
    if (a < NA_) {
        const float* p = maxvis + (((size_t)x * B_ + y) * NA_ + a) * T_;
        float ws = 0.0f, ss = 0.0f;
        #pragma unroll
        for (int t = 0; t < T_; ++t) {
            float mv  = p[t];
            float rd  = mv - th;
            float sel = fmaxf(rd, 0.0f) * scale;
            ws += mv * sel;
            ss += sel;
            if (rd > 0.0f) cnt += 1.0f;
            if (x == y) selsum += 0.5f * (tanhf(20.0f * rd) + 1.0f);
        }
        token = ws / fmaxf(ss, 1e-6f);
    }
    #pragma unroll
    for (int off = 32; off; off >>= 1) {
        token  += __shfl_xor(token,  off, 64);
        cnt    += __shfl_xor(cnt,    off, 64);
        selsum += __shfl_xor(selsum, off, 64);
    }
    if (threadIdx.x == 0) {
        clipSims[x * B_ + y] = token / (float)NA_;
        atomicAdd(&accs[1], cnt);
        if (x == y) atomicAdd(&accs[2], selsum);
    }
    __threadfence();                      // release
    unsigned last = 0;
    if (threadIdx.x == 0) {
        unsigned v = atomicAdd((unsigned int*)(accs + 3), 1u);
        last = ((v % (unsigned)(B_ * B_)) == (unsigned)(B_ * B_ - 1));
    }
    last = __shfl((int)last, 0, 64);
    if (!last) return;
    __threadfence();                      // acquire

    __shared__ float cs[B_ * B_];
    int tid = threadIdx.x;
    for (int i = tid; i < B_ * B_; i += 64) cs[i] = clipSims[i];
    __syncthreads();
    float lsum = 0.0f;
    if (tid < B_) {
        int i = tid;
        float m = -1e30f;
        for (int j = 0; j < B_; ++j) m = fmaxf(m, cs[i * B_ + j]);
        float e = 0.0f;
        for (int j = 0; j < B_; ++j) e += expf(cs[i * B_ + j] - m);
        float la = m + logf(e) - cs[i * B_ + i];
        float m2 = -1e30f;
        for (int j = 0; j < B_; ++j) m2 = fmaxf(m2, cs[j * B_ + i]);
        float e2 = 0.0f;
        for (int j = 0; j < B_; ++j) e2 += expf(cs[j * B_ + i] - m2);
        float lv = m2 + logf(e2) - cs[i * B_ + i];
        lsum = la + lv;
    }
    #pragma unroll
    for (int off = 32; off; off >>= 1) lsum += __shfl_xor(lsum, off, 64);
    if (tid == 0) {
        float contrastive = lsum / (float)B_ * 0.5f;
        float temp = tempPtr[0], scl = scalePtr[0];
        float th2 = 1.0f / (1.0f + expf(-thrPtr[0]));
        float l_nonneg = accs[0] / 56448000.0f;   // B*B*NA*T*NV
        float logt = logf(temp);
        float tl  = fmaxf(-logt, 0.0f);
        float thi = fmaxf(logt - logf(4.0f), 0.0f);
        float l_cal = tl * tl + thi * thi;
        float t1 = fmaxf(th2 - 0.9f, 0.0f), t2 = fmaxf(0.1f - th2, 0.0f);
        float l_thr = t1 * t1 + t2 * t2;
        float s1 = fmaxf(scl - 20.0f, 0.0f), s2 = fmaxf(1.0f - scl, 0.0f);
        float l_scale = s1 * s1 + s2 * s2;
        float reg = 0.15f * l_nonneg + 2.0f * l_cal + 0.1f * l_thr + 0.1f * l_scale;
        float frac   = accs[1] / 288000.0f;       // B*B*NA*T
        float selrew = -0.1f * log1pf(accs[2] / 12000.0f); // B*NA*T
        out[0] = selrew + contrastive + reg;
        out[1] = contrastive;
        out[2] = reg;
        out[3] = frac;
        out[4] = selrew;
    }
}

extern "C" void kernel_launch(void* const* d_in, const int* in_sizes, int n_in,
                              void* d_out, int out_size, void* d_ws, size_t ws_size,
                              hipStream_t stream) {
    const float* audio  = (const float*)d_in[0];  // (24,50,512)
    const float* visual = (const float*)d_in[1];  // (24,10,196,512)
    const float* temp   = (const float*)d_in[2];
    const float* scale  = (const float*)d_in[3];
    const float* thr    = (const float*)d_in[4];
    float* out = (float*)d_out;

    unsigned char* wsb = (unsigned char*)d_ws;
    unsigned short* Abf = (unsigned short*)wsb;                       // 1280*512*2
    unsigned short* Vbf = (unsigned short*)(wsb + 1310720);           // 53760*512*2
    float* maxvis   = (float*)(wsb + 1310720 + 55050240);             // 288000 floats
    float* clipSims = (float*)(wsb + 1310720 + 55050240 + 1152000);   // 576 floats
    float* accs     = clipSims + 576;                                 // [nonneg, frac, sel, counter]

    normconv_kernel<<<ABLK + VROWS / 4, 256, 0, stream>>>(audio, visual, temp, Abf, Vbf, accs);

    dim3 grid(MPAD / 128, YT_);
    simred_kernel<<<grid, 256, 0, stream>>>(Abf, Vbf, maxvis, accs);

    aggfin_kernel<<<B_ * B_, 64, 0, stream>>>(maxvis, thr, scale, temp, clipSims, accs, out);
}

// Round 12
// 272.321 us; speedup vs baseline: 1.0339x; 1.0339x over previous
//
#include <hip/hip_runtime.h>
#include <math.h>

#define B_   24
#define NA_  50
#define T_   10
#define NV_  196
#define D_   512
#define M_   1200          // B*NA audio rows
#define MPAD 1280          // padded to 5 tiles of 256
#define NVP  224           // 196 padded to 14*16
#define YT_  240           // B*T
#define VROWS (YT_ * NVP)  // 53760 padded visual rows
#define ABLK 320           // MPAD/4 blocks handle audio in fused normconv

#define NT    16           // K-steps (BK=32)
#define BUFB  32768u       // per-step buffer: A 16KB + V 14KB + 2KB scratch (dummy target)
#define VBASE 16384u

typedef __bf16 bf16x8 __attribute__((ext_vector_type(8)));
typedef float  f32x4  __attribute__((ext_vector_type(4)));
typedef unsigned short ushort8 __attribute__((ext_vector_type(8)));

__device__ __forceinline__ unsigned short f2bf(float f) {
    unsigned u = __float_as_uint(f);
    u += 0x7FFF + ((u >> 16) & 1);       // RNE
    return (unsigned short)(u >> 16);
}

__device__ __forceinline__ void gload16(const void* g, void* l) {
    __builtin_amdgcn_global_load_lds(
        (const __attribute__((address_space(1))) unsigned int*)g,
        (__attribute__((address_space(3))) unsigned int*)l, 16, 0, 0);
}

// ---- fused L2-normalize + bf16 convert for BOTH inputs, + accs/counter zeroing ----
__global__ void normconv_kernel(const float* __restrict__ a,
                                const float* __restrict__ vf,
                                const float* __restrict__ tempPtr,
                                unsigned short* __restrict__ Abf,
                                unsigned short* __restrict__ Vbf,
                                float* __restrict__ accs) {
    if (blockIdx.x == 0 && threadIdx.x < 4) accs[threadIdx.x] = 0.0f; // [nonneg,frac,sel,counter]
    int w = threadIdx.x >> 6, lane = threadIdx.x & 63;
    int bid = blockIdx.x;
    const float* src = nullptr;
    ushort8* dst;
    float tscale = 1.0f;
    if (bid < ABLK) {
        int row = bid * 4 + w;                 // < MPAD
        dst = (ushort8*)(Abf + (size_t)row * D_ + lane * 8);
        if (row < M_) { src = a + (size_t)row * D_ + lane * 8; tscale = tempPtr[0]; }
    } else {
        int row = (bid - ABLK) * 4 + w;        // < VROWS
        dst = (ushort8*)(Vbf + (size_t)row * D_ + lane * 8);
        int yt = row / NVP, vv = row - yt * NVP;
        if (vv < NV_) src = vf + ((size_t)yt * NV_ + vv) * D_ + lane * 8;
    }
    if (src) {
        float4 u = *(const float4*)src;
        float4 v = *(const float4*)(src + 4);
        float s = u.x*u.x + u.y*u.y + u.z*u.z + u.w*u.w
                + v.x*v.x + v.y*v.y + v.z*v.z + v.w*v.w;
        #pragma unroll
        for (int off = 32; off; off >>= 1) s += __shfl_xor(s, off, 64);
        float sc = 1.0f / (fmaxf(sqrtf(s), 1e-12f) * tscale);
        ushort8 o;
        o[0]=f2bf(u.x*sc); o[1]=f2bf(u.y*sc); o[2]=f2bf(u.z*sc); o[3]=f2bf(u.w*sc);
        o[4]=f2bf(v.x*sc); o[5]=f2bf(v.y*sc); o[6]=f2bf(v.z*sc); o[7]=f2bf(v.w*sc);
        *dst = o;
    } else {
        ushort8 z = (ushort8)0;
        *dst = z;
    }
}

// ---- MFMA GEMM + fused max/clip reductions: TRUE counted-vmcnt (never 0) ----
// R10 (95us best) drained vmcnt to 0 every step - the m97 issue-then-drain
// pattern at depth 1. R11 falsified the two-block alternative (112us). This
// version keeps R10's single 8-wave block / 256x224 geometry and goes DEPTH-2:
// triple-buffered LDS, STAGE(t+3) in flight across two steps, per-step wait
// vmcnt(4) (retires own STAGE(t+1) loads only; STAGE(t+2)'s stay in flight;
// uniform 4 loads/wave incl. dummies makes the count exact). vmcnt reaches 0
// only at the tail (t=14). RAW: each wave retires its own STAGE(t+1) BEFORE
// s_barrier => after barrier the whole buffer is valid. WAR: lgkmcnt(0) +
// barrier precede re-staging the just-read buffer. XCD bijective swizzle
// (FETCH 229->32MB, R3) + both-sides 16B-granule XOR LDS swizzle (R1) kept.
#define RD_FRAGS(AF, BV, BASE)                                                  \
    _Pragma("unroll") for (int i = 0; i < 4; ++i)                               \
        AF[i] = *(const bf16x8*)((BASE) + aoff[i]);                             \
    _Pragma("unroll") for (int j = 0; j < 7; ++j)                               \
        BV[j] = *(const bf16x8*)((BASE) + boff[j]);

#define MFMA_ALL(AF, BV)                                                        \
    _Pragma("unroll") for (int i = 0; i < 4; ++i)                               \
        _Pragma("unroll") for (int j = 0; j < 7; ++j)                           \
            acc[i][j] = __builtin_amdgcn_mfma_f32_16x16x32_bf16(AF[i], BV[j], acc[i][j], 0, 0, 0);

#define STAGE_T(T, BASEOFF)                                                     \
    _Pragma("unroll") for (int k = 0; k < 4; ++k)                               \
        gload16(gp[k] + (T) * 32, (void*)(lds + (BASEOFF) + loff[k]));

__global__ __launch_bounds__(512, 1) void simred_kernel(
    const unsigned short* __restrict__ Abf, const unsigned short* __restrict__ Vbf,
    float* __restrict__ maxvis, float* __restrict__ accNonneg)
{
    __shared__ __align__(16) unsigned char lds[3 * BUFB];   // 96KB triple buffer
    float* maxredp = (float*)(lds + 30720);          // 512 f32 in buf0 scratch (post-loop reuse)
    float* redbufp = (float*)(lds + BUFB + 30720);   // 8 f32 in buf1 scratch

    const int tid  = threadIdx.x;
    const int lane = tid & 63;
    const int w    = tid >> 6;     // 8 waves
    const int lrow = lane >> 2;    // staging: row within 16-row unit
    const int lcol = lane & 3;     // staging: 16B granule within 64B row-slice
    const int q    = lane >> 4;    // frag quad
    const int m16  = lane & 15;
    const int wr   = w & 3;        // wave row quarter (64 rows)
    const int wc   = w >> 2;       // wave col half (112 cols)

    // XCD-aware bijective remap: 1200 blocks, 8 XCDs, 150/XCD (yt-partitioned)
    const int lin = blockIdx.y * gridDim.x + blockIdx.x;
    const int swz = (lin & 7) * 150 + (lin >> 3);
    const int bx  = swz % 5;
    const int yt  = swz / 5;
    const int rowA0 = bx * 256;
    const size_t vRow0 = (size_t)yt * NVP;

    // staging units (1KB each): 0..15 = A rows, 16..29 = V rows, 30..31 dummy
    // (uniform 4 loads/wave -> exact per-wave vmcnt immediates). Source granule
    // pre-swizzled; LDS dest linear (both-sides rule).
    const int scol = lcol ^ ((lrow >> 1) & 3);
    const unsigned short* gp[4];
    unsigned loff[4];
    #pragma unroll
    for (int k = 0; k < 4; ++k) {
        int u = w + 8 * k;
        if (u < 16)      gp[k] = Abf + ((size_t)(rowA0 + u * 16 + lrow)) * D_ + scol * 8;
        else if (u < 30) gp[k] = Vbf + (vRow0 + (size_t)((u - 16) * 16 + lrow)) * D_ + scol * 8;
        else             gp[k] = Abf + (size_t)lane * 8;   // dummy: valid mem, never read
        loff[k] = (unsigned)u * 1024u;
    }

    // fragment read offsets (row*64B + swizzled 16B granule)
    const unsigned rsw = (unsigned)((m16 >> 1) & 3) * 16u;
    unsigned aoff[4], boff[7];
    #pragma unroll
    for (int i = 0; i < 4; ++i)
        aoff[i] = (unsigned)(wr * 64 + i * 16 + m16) * 64u + (((unsigned)q * 16u) ^ rsw);
    #pragma unroll
    for (int j = 0; j < 7; ++j)
        boff[j] = VBASE + (unsigned)(wc * 112 + j * 16 + m16) * 64u + (((unsigned)q * 16u) ^ rsw);

    f32x4 acc[4][7];
    #pragma unroll
    for (int i = 0; i < 4; ++i)
        #pragma unroll
        for (int j = 0; j < 7; ++j) acc[i][j] = (f32x4)0.0f;

    bf16x8 afA[4], bvA[7], afB[4], bvB[7];

    // prologue: STAGE(0..2) -> b0..b2 (12 loads out); retire own STAGE(0)
    // (vmcnt(8)) then rendezvous; frags(0) -> set A.
    STAGE_T(0, 0u)
    STAGE_T(1, BUFB)
    STAGE_T(2, 2u * BUFB)
    asm volatile("s_waitcnt vmcnt(8)\ns_barrier" ::: "memory");
    RD_FRAGS(afA, bvA, lds)

    #pragma unroll
    for (int tp = 0; tp < 8; ++tp) {
        const int t = 2 * tp;                              // compile-time after unroll
        const unsigned c0 = (unsigned)(t % 3) * BUFB;      // holds frags(t)   (read last step)
        const unsigned c1 = (unsigned)((t + 1) % 3) * BUFB;
        const unsigned c2 = (unsigned)((t + 2) % 3) * BUFB;
        // ---- even step t: retire STAGE(t+1), keep STAGE(t+2) flying ----
        if (t <= 12) { asm volatile("s_waitcnt vmcnt(4) lgkmcnt(0)\ns_barrier" ::: "memory"); }
        else         { asm volatile("s_waitcnt vmcnt(0) lgkmcnt(0)\ns_barrier" ::: "memory"); } // t==14
        if (t + 3 < NT) { STAGE_T(t + 3, c0) }             // -> buffer read last step (WAR-safe)
        RD_FRAGS(afB, bvB, lds + c1)                       // frags(t+1): STAGE(t+1) retired
        __builtin_amdgcn_s_setprio(1);
        MFMA_ALL(afA, bvA)
        __builtin_amdgcn_s_setprio(0);
        // ---- odd step t+1 ----
        if (t + 1 <= 13) { asm volatile("s_waitcnt vmcnt(4) lgkmcnt(0)\ns_barrier" ::: "memory"); }
        else             { asm volatile("s_waitcnt lgkmcnt(0)\ns_barrier" ::: "memory"); }       // t+1==15
        if (t + 4 < NT) { STAGE_T(t + 4, c1) }
        if (t + 2 < NT) { RD_FRAGS(afA, bvA, lds + c2) }
        __builtin_amdgcn_s_setprio(1);
        MFMA_ALL(afB, bvB)
        __builtin_amdgcn_s_setprio(0);
    }

    // ---- clip(s,-20,0)^2 partial sum (zero-padded rows/cols contribute exactly 0) ----
    float cs = 0.0f;
    #pragma unroll
    for (int i = 0; i < 4; ++i)
        #pragma unroll
        for (int j = 0; j < 7; ++j)
            #pragma unroll
            for (int r = 0; r < 4; ++r) {
                float v = acc[i][j][r];
                float cv = fminf(fmaxf(v, -20.0f), 0.0f);
                cs += cv * cv;
            }
    #pragma unroll
    for (int off = 32; off; off >>= 1) cs += __shfl_xor(cs, off, 64);
    if (lane == 0) redbufp[w] = cs;

    // ---- per-row max over valid cols (C/D layout: col=lane&15, row=q*4+reg) ----
    bool colv[7];
    #pragma unroll
    for (int j = 0; j < 7; ++j) colv[j] = (wc * 112 + j * 16 + m16) < NV_;
    #pragma unroll
    for (int i = 0; i < 4; ++i) {
        float mx[4] = {-3e38f, -3e38f, -3e38f, -3e38f};
        #pragma unroll
        for (int j = 0; j < 7; ++j)
            #pragma unroll
            for (int r = 0; r < 4; ++r)
                mx[r] = fmaxf(mx[r], colv[j] ? acc[i][j][r] : -3e38f);
        #pragma unroll
        for (int r = 0; r < 4; ++r) {
            float mm = mx[r];
            #pragma unroll
            for (int off = 1; off <= 8; off <<= 1) mm = fmaxf(mm, __shfl_xor(mm, off, 64));
            if (m16 == 0) maxredp[wc * 256 + wr * 64 + i * 16 + q * 4 + r] = mm;
        }
    }
    __syncthreads();
    if (tid == 0) atomicAdd(accNonneg, redbufp[0] + redbufp[1] + redbufp[2] + redbufp[3]
                                     + redbufp[4] + redbufp[5] + redbufp[6] + redbufp[7]);
    if (tid < 256) {
        float mm = fmaxf(maxredp[tid], maxredp[256 + tid]);
        int R = rowA0 + tid;
        if (R < M_) {
            int x = R / NA_, a = R - x * NA_;
            int y = yt / T_, t = yt - y * T_;
            maxvis[(((size_t)x * B_ + y) * NA_ + a) * T_ + t] = mm;
        }
    }
}

// ---------------- aggregation + last-block finalize ----------------
__global__ void aggfin_kernel(const float* __restrict__ maxvis,
                              const float* __restrict__ thrPtr,
                              const float* __restrict__ scalePtr,
                              const float* __restrict__ tempPtr,
                              float* __restrict__ clipSims,
                              float* __restrict__ accs,
                              float* __restrict__ out)
{
    int xy = blockIdx.x;
    int x = xy / B_, y = xy % B_;
    int a = threadIdx.x;
    float th    = 1.0f / (1.0f + expf(-thrPtr[0]));
    float scale = scalePtr[0];
    float token = 0.0f, cnt = 0.0f, selsum = 0.0f;
    if (a < NA_) {
        const float* p = maxvis + (((size_t)x * B_ + y) * NA_ + a) * T_;
        float ws = 0.0f, ss = 0.0f;
        #pragma unroll
        for (int t = 0; t < T_; ++t) {
            float mv  = p[t];
            float rd  = mv - th;
            float sel = fmaxf(rd, 0.0f) * scale;
            ws += mv * sel;
            ss += sel;
            if (rd > 0.0f) cnt += 1.0f;
            if (x == y) selsum += 0.5f * (tanhf(20.0f * rd) + 1.0f);
        }
        token = ws / fmaxf(ss, 1e-6f);
    }
    #pragma unroll
    for (int off = 32; off; off >>= 1) {
        token  += __shfl_xor(token,  off, 64);
        cnt    += __shfl_xor(cnt,    off, 64);
        selsum += __shfl_xor(selsum, off, 64);
    }
    if (threadIdx.x == 0) {
        clipSims[x * B_ + y] = token / (float)NA_;
        atomicAdd(&accs[1], cnt);
        if (x == y) atomicAdd(&accs[2], selsum);
    }
    __threadfence();                      // release
    unsigned last = 0;
    if (threadIdx.x == 0) {
        unsigned v = atomicAdd((unsigned int*)(accs + 3), 1u);
        last = ((v % (unsigned)(B_ * B_)) == (unsigned)(B_ * B_ - 1));
    }
    last = __shfl((int)last, 0, 64);
    if (!last) return;
    __threadfence();                      // acquire

    __shared__ float cs[B_ * B_];
    int tid = threadIdx.x;
    for (int i = tid; i < B_ * B_; i += 64) cs[i] = clipSims[i];
    __syncthreads();
    float lsum = 0.0f;
    if (tid < B_) {
        int i = tid;
        float m = -1e30f;
        for (int j = 0; j < B_; ++j) m = fmaxf(m, cs[i * B_ + j]);
        float e = 0.0f;
        for (int j = 0; j < B_; ++j) e += expf(cs[i * B_ + j] - m);
        float la = m + logf(e) - cs[i * B_ + i];
        float m2 = -1e30f;
        for (int j = 0; j < B_; ++j) m2 = fmaxf(m2, cs[j * B_ + i]);
        float e2 = 0.0f;
        for (int j = 0; j < B_; ++j) e2 += expf(cs[j * B_ + i] - m2);
        float lv = m2 + logf(e2) - cs[i * B_ + i];
        lsum = la + lv;
    }
    #pragma unroll
    for (int off = 32; off; off >>= 1) lsum += __shfl_xor(lsum, off, 64);
    if (tid == 0) {
        float contrastive = lsum / (float)B_ * 0.5f;
        float temp = tempPtr[0], scl = scalePtr[0];
        float th2 = 1.0f / (1.0f + expf(-thrPtr[0]));
        float l_nonneg = accs[0] / 56448000.0f;   // B*B*NA*T*NV
        float logt = logf(temp);
        float tl  = fmaxf(-logt, 0.0f);
        float thi = fmaxf(logt - logf(4.0f), 0.0f);
        float l_cal = tl * tl + thi * thi;
        float t1 = fmaxf(th2 - 0.9f, 0.0f), t2 = fmaxf(0.1f - th2, 0.0f);
        float l_thr = t1 * t1 + t2 * t2;
        float s1 = fmaxf(scl - 20.0f, 0.0f), s2 = fmaxf(1.0f - scl, 0.0f);
        float l_scale = s1 * s1 + s2 * s2;
        float reg = 0.15f * l_nonneg + 2.0f * l_cal + 0.1f * l_thr + 0.1f * l_scale;
        float frac   = accs[1] / 288000.0f;       // B*B*NA*T
        float selrew = -0.1f * log1pf(accs[2] / 12000.0f); // B*NA*T
        out[0] = selrew + contrastive + reg;
        out[1] = contrastive;
        out[2] = reg;
        out[3] = frac;
        out[4] = selrew;
    }
}

extern "C" void kernel_launch(void* const* d_in, const int* in_sizes, int n_in,
                              void* d_out, int out_size, void* d_ws, size_t ws_size,
                              hipStream_t stream) {
    const float* audio  = (const float*)d_in[0];  // (24,50,512)
    const float* visual = (const float*)d_in[1];  // (24,10,196,512)
    const float* temp   = (const float*)d_in[2];
    const float* scale  = (const float*)d_in[3];
    const float* thr    = (const float*)d_in[4];
    float* out = (float*)d_out;

    unsigned char* wsb = (unsigned char*)d_ws;
    unsigned short* Abf = (unsigned short*)wsb;                       // 1280*512*2
    unsigned short* Vbf = (unsigned short*)(wsb + 1310720);           // 53760*512*2
    float* maxvis   = (float*)(wsb + 1310720 + 55050240);             // 288000 floats
    float* clipSims = (float*)(wsb + 1310720 + 55050240 + 1152000);   // 576 floats
    float* accs     = clipSims + 576;                                 // [nonneg, frac, sel, counter]

    normconv_kernel<<<ABLK + VROWS / 4, 256, 0, stream>>>(audio, visual, temp, Abf, Vbf, accs);

    dim3 grid(MPAD / 256, YT_);
    simred_kernel<<<grid, 512, 0, stream>>>(Abf, Vbf, maxvis, accs);

    aggfin_kernel<<<B_ * B_, 64, 0, stream>>>(maxvis, thr, scale, temp, clipSims, accs, out);
}

// Round 13
// 265.256 us; speedup vs baseline: 1.0614x; 1.0266x over previous
//
#include <hip/hip_runtime.h>
#include <math.h>

#define B_   24
#define NA_  50
#define T_   10
#define NV_  196
#define D_   512
#define M_   1200          // B*NA audio rows
#define MPAD 1280          // padded to 5 tiles of 256
#define NVP  224           // 196 padded to 14*16
#define YT_  240           // B*T
#define VROWS (YT_ * NVP)  // 53760 padded visual rows
#define ABLK 320           // MPAD/4 blocks handle audio in fused normconv

#define NT    8            // K-steps (BK=64)
#define BUFB  65536u       // per-step buffer: 64 units x 1KB (A 32 + V 28 + 4 dummy)
#define VBASE 32768u

typedef __bf16 bf16x8 __attribute__((ext_vector_type(8)));
typedef float  f32x4  __attribute__((ext_vector_type(4)));
typedef unsigned short ushort8 __attribute__((ext_vector_type(8)));

__device__ __forceinline__ unsigned short f2bf(float f) {
    unsigned u = __float_as_uint(f);
    u += 0x7FFF + ((u >> 16) & 1);       // RNE
    return (unsigned short)(u >> 16);
}

__device__ __forceinline__ void gload16(const void* g, void* l) {
    __builtin_amdgcn_global_load_lds(
        (const __attribute__((address_space(1))) unsigned int*)g,
        (__attribute__((address_space(3))) unsigned int*)l, 16, 0, 0);
}

// ---- fused L2-normalize + bf16 convert for BOTH inputs, + accs/counter zeroing ----
__global__ void normconv_kernel(const float* __restrict__ a,
                                const float* __restrict__ vf,
                                const float* __restrict__ tempPtr,
                                unsigned short* __restrict__ Abf,
                                unsigned short* __restrict__ Vbf,
                                float* __restrict__ accs) {
    if (blockIdx.x == 0 && threadIdx.x < 4) accs[threadIdx.x] = 0.0f; // [nonneg,frac,sel,counter]
    int w = threadIdx.x >> 6, lane = threadIdx.x & 63;
    int bid = blockIdx.x;
    const float* src = nullptr;
    ushort8* dst;
    float tscale = 1.0f;
    if (bid < ABLK) {
        int row = bid * 4 + w;                 // < MPAD
        dst = (ushort8*)(Abf + (size_t)row * D_ + lane * 8);
        if (row < M_) { src = a + (size_t)row * D_ + lane * 8; tscale = tempPtr[0]; }
    } else {
        int row = (bid - ABLK) * 4 + w;        // < VROWS
        dst = (ushort8*)(Vbf + (size_t)row * D_ + lane * 8);
        int yt = row / NVP, vv = row - yt * NVP;
        if (vv < NV_) src = vf + ((size_t)yt * NV_ + vv) * D_ + lane * 8;
    }
    if (src) {
        float4 u = *(const float4*)src;
        float4 v = *(const float4*)(src + 4);
        float s = u.x*u.x + u.y*u.y + u.z*u.z + u.w*u.w
                + v.x*v.x + v.y*v.y + v.z*v.z + v.w*v.w;
        #pragma unroll
        for (int off = 32; off; off >>= 1) s += __shfl_xor(s, off, 64);
        float sc = 1.0f / (fmaxf(sqrtf(s), 1e-12f) * tscale);
        ushort8 o;
        o[0]=f2bf(u.x*sc); o[1]=f2bf(u.y*sc); o[2]=f2bf(u.z*sc); o[3]=f2bf(u.w*sc);
        o[4]=f2bf(v.x*sc); o[5]=f2bf(v.y*sc); o[6]=f2bf(v.z*sc); o[7]=f2bf(v.w*sc);
        *dst = o;
    } else {
        ushort8 z = (ushort8)0;
        *dst = z;
    }
}

// ---- MFMA GEMM + fused max/clip reductions: BK=64, 8 steps, 1 barrier/step ----
// R12 back-solve: per-step 2880cyc vs matrix 1086 + LDS 1050 (overlappable)
// -> ~1700cyc/step of per-step fixed cost (rendezvous + refill). BK=64 halves
// the step count at identical total MFMA/ds_read work: 2x64KB buffers of
// 8-row x 128B units (64 units, 4 dummies -> uniform 8 loads/wave), depth-1
// prefetch whose vmcnt(0) at step top is issued a FULL step (~3000cyc) ahead
// (covered, not a drain). Swizzle for 128B rows, both-sides (rule 21):
// source granule g ^= (lane>>3); read pos = (kk*4+q) ^ (m16&7), where the
// kk term folds to addr^64. Each 8-lane group covers all 8 granules -> all
// 32 banks. XCD bijective swizzle retained (FETCH 229->32MB, R3-verified).
#define STAGE_T(T, BASEOFF)                                                     \
    _Pragma("unroll") for (int k = 0; k < 8; ++k)                               \
        gload16(gp[k] + (T) * 64, (void*)(lds + (BASEOFF) + loff[k]));

#define RD_K(BASE, KOFS)                                                        \
    _Pragma("unroll") for (int i = 0; i < 4; ++i)                               \
        af[i] = *(const bf16x8*)((BASE) + (aoff[i] ^ (KOFS)));                  \
    _Pragma("unroll") for (int j = 0; j < 7; ++j)                               \
        bv[j] = *(const bf16x8*)((BASE) + (boff[j] ^ (KOFS)));

#define MF_ALL()                                                                \
    _Pragma("unroll") for (int i = 0; i < 4; ++i)                               \
        _Pragma("unroll") for (int j = 0; j < 7; ++j)                           \
            acc[i][j] = __builtin_amdgcn_mfma_f32_16x16x32_bf16(af[i], bv[j], acc[i][j], 0, 0, 0);

__global__ __launch_bounds__(512, 1) void simred_kernel(
    const unsigned short* __restrict__ Abf, const unsigned short* __restrict__ Vbf,
    float* __restrict__ maxvis, float* __restrict__ accNonneg)
{
    __shared__ __align__(16) unsigned char lds[2 * BUFB];   // 128KB double buffer
    float* maxredp = (float*)(lds + 61440);          // 512 f32 in buf0 dummy area (post-loop)
    float* redbufp = (float*)(lds + BUFB + 61440);   // 8 f32 in buf1 dummy area

    const int tid  = threadIdx.x;
    const int lane = tid & 63;
    const int w    = tid >> 6;     // 8 waves
    const int lr8  = lane >> 3;    // staging: row within 8-row unit
    const int q    = lane >> 4;    // frag quad (k-segment q*8 within K=32)
    const int m16  = lane & 15;
    const int wr   = w & 3;        // wave row quarter (64 rows)
    const int wc   = w >> 2;       // wave col half (112 cols)

    // XCD-aware bijective remap: 1200 blocks, 8 XCDs, 150/XCD (yt-partitioned)
    const int lin = blockIdx.y * gridDim.x + blockIdx.x;
    const int swz = (lin & 7) * 150 + (lin >> 3);
    const int bx  = swz % 5;
    const int yt  = swz / 5;
    const int rowA0 = bx * 256;
    const size_t vRow0 = (size_t)yt * NVP;

    // staging units (1KB = 8 rows x 128B): u 0..31 = A rows u*8.., 32..59 =
    // V rows (u-32)*8.., 60..63 dummy (uniform 8 loads/wave). Source granule
    // pre-swizzled g^=(lane>>3); LDS dest linear (both-sides rule).
    const int scol = (lane & 7) ^ lr8;            // swizzled 16B granule 0..7
    const unsigned short* gp[8];
    unsigned loff[8];
    #pragma unroll
    for (int k = 0; k < 8; ++k) {
        int u = w + 8 * k;
        if (u < 32)      gp[k] = Abf + ((size_t)(rowA0 + u * 8 + lr8)) * D_ + scol * 8;
        else if (u < 60) gp[k] = Vbf + (vRow0 + (size_t)((u - 32) * 8 + lr8)) * D_ + scol * 8;
        else             gp[k] = Abf + (size_t)lane * 8;   // dummy: valid mem, never read
        loff[k] = (unsigned)u * 1024u;
    }

    // fragment read offsets: row*128B + swizzled granule ((q)^(m16&7))*16 for
    // kk=0; kk=1 is the same address ^64 (bit-2 of the granule).
    const unsigned key = (unsigned)(m16 & 7);
    unsigned aoff[4], boff[7];
    #pragma unroll
    for (int i = 0; i < 4; ++i)
        aoff[i] = (unsigned)(wr * 64 + i * 16 + m16) * 128u + (((unsigned)q ^ key) * 16u);
    #pragma unroll
    for (int j = 0; j < 7; ++j)
        boff[j] = VBASE + (unsigned)(wc * 112 + j * 16 + m16) * 128u + (((unsigned)q ^ key) * 16u);

    f32x4 acc[4][7];
    #pragma unroll
    for (int i = 0; i < 4; ++i)
        #pragma unroll
        for (int j = 0; j < 7; ++j) acc[i][j] = (f32x4)0.0f;

    // prologue: STAGE(0) -> buf0
    STAGE_T(0, 0u)

    #pragma unroll
    for (int t = 0; t < NT; ++t) {
        const unsigned char* buf = lds + (unsigned)(t & 1) * BUFB;
        // STAGE(t) resident everywhere (issued a full step ago for t>0; the
        // lgkm half is free: prior MFMA operand waits already drained it).
        asm volatile("s_waitcnt vmcnt(0) lgkmcnt(0)\ns_barrier" ::: "memory");
        if (t + 1 < NT) { STAGE_T(t + 1, (unsigned)((t + 1) & 1) * BUFB) }
        bf16x8 af[4], bv[7];
        __builtin_amdgcn_s_setprio(1);
        RD_K(buf, 0u)      // kk=0 frags; compiler interleaves lgkm with MFMA
        MF_ALL()
        RD_K(buf, 64u)     // kk=1 frags
        MF_ALL()
        __builtin_amdgcn_s_setprio(0);
    }

    // ---- clip(s,-20,0)^2 partial sum (zero-padded rows/cols contribute exactly 0) ----
    float cs = 0.0f;
    #pragma unroll
    for (int i = 0; i < 4; ++i)
        #pragma unroll
        for (int j = 0; j < 7; ++j)
            #pragma unroll
            for (int r = 0; r < 4; ++r) {
                float v = acc[i][j][r];
                float cv = fminf(fmaxf(v, -20.0f), 0.0f);
                cs += cv * cv;
            }
    #pragma unroll
    for (int off = 32; off; off >>= 1) cs += __shfl_xor(cs, off, 64);
    __syncthreads();                       // all staging writes retired; dummy area safe
    if (lane == 0) redbufp[w] = cs;

    // ---- per-row max over valid cols (C/D layout: col=lane&15, row=q*4+reg) ----
    bool colv[7];
    #pragma unroll
    for (int j = 0; j < 7; ++j) colv[j] = (wc * 112 + j * 16 + m16) < NV_;
    #pragma unroll
    for (int i = 0; i < 4; ++i) {
        float mx[4] = {-3e38f, -3e38f, -3e38f, -3e38f};
        #pragma unroll
        for (int j = 0; j < 7; ++j)
            #pragma unroll
            for (int r = 0; r < 4; ++r)
                mx[r] = fmaxf(mx[r], colv[j] ? acc[i][j][r] : -3e38f);
        #pragma unroll
        for (int r = 0; r < 4; ++r) {
            float mm = mx[r];
            #pragma unroll
            for (int off = 1; off <= 8; off <<= 1) mm = fmaxf(mm, __shfl_xor(mm, off, 64));
            if (m16 == 0) maxredp[wc * 256 + wr * 64 + i * 16 + q * 4 + r] = mm;
        }
    }
    __syncthreads();
    if (tid == 0) atomicAdd(accNonneg, redbufp[0] + redbufp[1] + redbufp[2] + redbufp[3]
                                     + redbufp[4] + redbufp[5] + redbufp[6] + redbufp[7]);
    if (tid < 256) {
        float mm = fmaxf(maxredp[tid], maxredp[256 + tid]);
        int R = rowA0 + tid;
        if (R < M_) {
            int x = R / NA_, a = R - x * NA_;
            int y = yt / T_, t = yt - y * T_;
            maxvis[(((size_t)x * B_ + y) * NA_ + a) * T_ + t] = mm;
        }
    }
}

// ---------------- aggregation + last-block finalize ----------------
__global__ void aggfin_kernel(const float* __restrict__ maxvis,
                              const float* __restrict__ thrPtr,
                              const float* __restrict__ scalePtr,
                              const float* __restrict__ tempPtr,
                              float* __restrict__ clipSims,
                              float* __restrict__ accs,
                              float* __restrict__ out)
{
    int xy = blockIdx.x;
    int x = xy / B_, y = xy % B_;
    int a = threadIdx.x;
    float th    = 1.0f / (1.0f + expf(-thrPtr[0]));
    float scale = scalePtr[0];
    float token = 0.0f, cnt = 0.0f, selsum = 0.0f;
    if (a < NA_) {
        const float* p = maxvis + (((size_t)x * B_ + y) * NA_ + a) * T_;
        float ws = 0.0f, ss = 0.0f;
        #pragma unroll
        for (int t = 0; t < T_; ++t) {
            float mv  = p[t];
            float rd  = mv - th;
            float sel = fmaxf(rd, 0.0f) * scale;
            ws += mv * sel;
            ss += sel;
            if (rd > 0.0f) cnt += 1.0f;
            if (x == y) selsum += 0.5f * (tanhf(20.0f * rd) + 1.0f);
        }
        token = ws / fmaxf(ss, 1e-6f);
    }
    #pragma unroll
    for (int off = 32; off; off >>= 1) {
        token  += __shfl_xor(token,  off, 64);
        cnt    += __shfl_xor(cnt,    off, 64);
        selsum += __shfl_xor(selsum, off, 64);
    }
    if (threadIdx.x == 0) {
        clipSims[x * B_ + y] = token / (float)NA_;
        atomicAdd(&accs[1], cnt);
        if (x == y) atomicAdd(&accs[2], selsum);
    }
    __threadfence();                      // release
    unsigned last = 0;
    if (threadIdx.x == 0) {
        unsigned v = atomicAdd((unsigned int*)(accs + 3), 1u);
        last = ((v % (unsigned)(B_ * B_)) == (unsigned)(B_ * B_ - 1));
    }
    last = __shfl((int)last, 0, 64);
    if (!last) return;
    __threadfence();                      // acquire

    __shared__ float cs[B_ * B_];
    int tid = threadIdx.x;
    for (int i = tid; i < B_ * B_; i += 64) cs[i] = clipSims[i];
    __syncthreads();
    float lsum = 0.0f;
    if (tid < B_) {
        int i = tid;
        float m = -1e30f;
        for (int j = 0; j < B_; ++j) m = fmaxf(m, cs[i * B_ + j]);
        float e = 0.0f;
        for (int j = 0; j < B_; ++j) e += expf(cs[i * B_ + j] - m);
        float la = m + logf(e) - cs[i * B_ + i];
        float m2 = -1e30f;
        for (int j = 0; j < B_; ++j) m2 = fmaxf(m2, cs[j * B_ + i]);
        float e2 = 0.0f;
        for (int j = 0; j < B_; ++j) e2 += expf(cs[j * B_ + i] - m2);
        float lv = m2 + logf(e2) - cs[i * B_ + i];
        lsum = la + lv;
    }
    #pragma unroll
    for (int off = 32; off; off >>= 1) lsum += __shfl_xor(lsum, off, 64);
    if (tid == 0) {
        float contrastive = lsum / (float)B_ * 0.5f;
        float temp = tempPtr[0], scl = scalePtr[0];
        float th2 = 1.0f / (1.0f + expf(-thrPtr[0]));
        float l_nonneg = accs[0] / 56448000.0f;   // B*B*NA*T*NV
        float logt = logf(temp);
        float tl  = fmaxf(-logt, 0.0f);
        float thi = fmaxf(logt - logf(4.0f), 0.0f);
        float l_cal = tl * tl + thi * thi;
        float t1 = fmaxf(th2 - 0.9f, 0.0f), t2 = fmaxf(0.1f - th2, 0.0f);
        float l_thr = t1 * t1 + t2 * t2;
        float s1 = fmaxf(scl - 20.0f, 0.0f), s2 = fmaxf(1.0f - scl, 0.0f);
        float l_scale = s1 * s1 + s2 * s2;
        float reg = 0.15f * l_nonneg + 2.0f * l_cal + 0.1f * l_thr + 0.1f * l_scale;
        float frac   = accs[1] / 288000.0f;       // B*B*NA*T
        float selrew = -0.1f * log1pf(accs[2] / 12000.0f); // B*NA*T
        out[0] = selrew + contrastive + reg;
        out[1] = contrastive;
        out[2] = reg;
        out[3] = frac;
        out[4] = selrew;
    }
}

extern "C" void kernel_launch(void* const* d_in, const int* in_sizes, int n_in,
                              void* d_out, int out_size, void* d_ws, size_t ws_size,
                              hipStream_t stream) {
    const float* audio  = (const float*)d_in[0];  // (24,50,512)
    const float* visual = (const float*)d_in[1];  // (24,10,196,512)
    const float* temp   = (const float*)d_in[2];
    const float* scale  = (const float*)d_in[3];
    const float* thr    = (const float*)d_in[4];
    float* out = (float*)d_out;

    unsigned char* wsb = (unsigned char*)d_ws;
    unsigned short* Abf = (unsigned short*)wsb;                       // 1280*512*2
    unsigned short* Vbf = (unsigned short*)(wsb + 1310720);           // 53760*512*2
    float* maxvis   = (float*)(wsb + 1310720 + 55050240);             // 288000 floats
    float* clipSims = (float*)(wsb + 1310720 + 55050240 + 1152000);   // 576 floats
    float* accs     = clipSims + 576;                                 // [nonneg, frac, sel, counter]

    normconv_kernel<<<ABLK + VROWS / 4, 256, 0, stream>>>(audio, visual, temp, Abf, Vbf, accs);

    dim3 grid(MPAD / 256, YT_);
    simred_kernel<<<grid, 512, 0, stream>>>(Abf, Vbf, maxvis, accs);

    aggfin_kernel<<<B_ * B_, 64, 0, stream>>>(maxvis, thr, scale, temp, clipSims, accs, out);
}